// Round 9
// baseline (30642.996 us; speedup 1.0000x reference)
//
#include <hip/hip_runtime.h>
#include <hip/hip_bf16.h>
#include <hip/hip_fp16.h>

typedef _Float16 f16;
typedef __attribute__((ext_vector_type(4))) _Float16 f16x4;
typedef __attribute__((ext_vector_type(8))) _Float16 f16x8;
typedef __attribute__((ext_vector_type(4))) float f32x4;

#define T_ 512
#define B_ 128
#define I_ 256
#define H_ 512
#define KA2 544     // Wat2 cols: [0,512) W_att | 512 b_att | 0
#define HP 520      // h_lds row pitch (f16): 65 x 16B -> odd 16B stride, no extra conflicts
#define TP 20

#define MFMA16(a,b,c) __builtin_amdgcn_mfma_f32_16x16x32_f16((a),(b),(c),0,0,0)

__device__ __forceinline__ float fast_exp(float x){
  return __builtin_amdgcn_exp2f(x * 1.4426950408889634f);
}
__device__ __forceinline__ float sigm(float x){
  return __builtin_amdgcn_rcpf(1.f + fast_exp(-x));
}
__device__ __forceinline__ float tanh_f(float x){
  return 1.f - 2.f * __builtin_amdgcn_rcpf(1.f + fast_exp(2.f * x));
}

// ---------------- prep: f16 copies of x, W_ih, and W_att(+bias col) ----------------
__global__ void k_prep(const float* __restrict__ x, const float* __restrict__ Wih,
                       const float* __restrict__ Watt, const float* __restrict__ batt,
                       f16* __restrict__ x16, f16* __restrict__ Wih16, f16* __restrict__ Wat2){
  const int n1 = B_ * T_ * I_;
  const int n2 = 3 * H_ * I_;
  const int n3 = H_ * KA2;
  const int tot = n1 + n2 + n3;
  for (int i = blockIdx.x * blockDim.x + threadIdx.x; i < tot; i += gridDim.x * blockDim.x){
    if (i < n1){
      x16[i] = (f16)x[i];
    } else if (i < n1 + n2){
      int j = i - n1;
      Wih16[j] = (f16)Wih[j];
    } else {
      int j = i - n1 - n2; int r = j / KA2, k = j % KA2;
      float v = (k < H_) ? Watt[r * H_ + k] : (k == H_ ? batt[r] : 0.f);
      Wat2[j] = (f16)v;
    }
  }
}

// ---------------- probe: (lane,reg)->(row,col) D mapping ----------------
__global__ void k_probe(int* __restrict__ rtab, int* __restrict__ ctab){
  __shared__ __align__(16) f16 A[16][32];
  __shared__ __align__(16) f16 BT[16][32];
  const int l = threadIdx.x, l16 = l & 15, lg = l >> 4;
  for (int i = l; i < 512; i += 64){ ((f16*)A)[i] = (f16)0.f; ((f16*)BT)[i] = (f16)0.f; }
  __syncthreads();
  if (l < 16){
    A[l][0]  = (f16)(float)(16 * l);
    A[l][1]  = (f16)1.f;
    BT[l][0] = (f16)1.f;
    BT[l][1] = (f16)(float)l;
  }
  __syncthreads();
  f16x8 a = *(const f16x8*)&A[l16][lg * 8];
  f16x8 b = *(const f16x8*)&BT[l16][lg * 8];
  f32x4 z; z[0]=0.f; z[1]=0.f; z[2]=0.f; z[3]=0.f;
  f32x4 d = MFMA16(a, b, z);
  #pragma unroll
  for (int q = 0; q < 4; ++q){
    int code = (int)(d[q] + 0.5f);
    rtab[l * 4 + q] = code >> 4;
    ctab[l * 4 + q] = code & 15;
  }
}

// ---------------- recurrence: 8 WGs x 1024 thr; W_hh register-resident; NO cross-WG sync --------
// WG g owns batch rows [16g,16g+16). Wave w (0..15) owns h-cols [32w,32w+32) for ALL 3 gates
// (weight rows {gate*512 + col}) -> gate nonlinearity is accumulator-local. h double-buffered in
// LDS; one __syncthreads per step. x-part precomputed per 32-step chunk into wave-private global
// scratch (same-WG produce+consume: no coherence protocol anywhere).
__global__ __launch_bounds__(1024) void k_rec(const f16* __restrict__ x16,
    const float* __restrict__ Whh, const float* __restrict__ bih, const float* __restrict__ bhh,
    const f16* __restrict__ Wih16, const int* __restrict__ rtab, const int* __restrict__ ctab,
    f16* __restrict__ scr, f16* __restrict__ hs){
  const int g   = blockIdx.x;
  const int b0  = g * 16;
  const int tid = threadIdx.x;
  const int w   = tid >> 6;
  const int lane = tid & 63, l16 = lane & 15, lg = lane >> 4;
  const int jw  = w * 32;

  __shared__ __align__(16) f16 hl[2][16][HP];
  for (int i = tid; i < 2 * 16 * HP; i += 1024) ((f16*)hl)[i] = (f16)0.f;

  int rt[4], ct[4];
  #pragma unroll
  for (int q = 0; q < 4; ++q){ rt[q] = rtab[lane*4+q]; ct[q] = ctab[lane*4+q]; }

  // ---- resident W_hh fragments: wh[gate][s][kt] (96 x f16x8 = 384 VGPR) ----
  f16x8 wh[3][2][16];
  #pragma unroll
  for (int gate = 0; gate < 3; ++gate)
    #pragma unroll
    for (int s = 0; s < 2; ++s){
      const float* wr = Whh + (size_t)(gate * H_ + jw + s * 16 + l16) * H_ + lg * 8;
      #pragma unroll
      for (int kt = 0; kt < 16; ++kt){
        f32x4 v0 = *(const f32x4*)(wr + kt * 32);
        f32x4 v1 = *(const f32x4*)(wr + kt * 32 + 4);
        f16x8 f;
        f[0]=(f16)v0[0]; f[1]=(f16)v0[1]; f[2]=(f16)v0[2]; f[3]=(f16)v0[3];
        f[4]=(f16)v1[0]; f[5]=(f16)v1[1]; f[6]=(f16)v1[2]; f[7]=(f16)v1[3];
        wh[gate][s][kt] = f;
      }
    }

  // ---- resident biases per output slot (s,q): col j = jw + s*16 + ct[q] ----
  float brc[2][4], bzc[2][4], bnx[2][4], bnh[2][4];
  #pragma unroll
  for (int s = 0; s < 2; ++s)
    #pragma unroll
    for (int q = 0; q < 4; ++q){
      int j = jw + s * 16 + ct[q];
      brc[s][q] = bih[j]          + bhh[j];
      bzc[s][q] = bih[j + H_]     + bhh[j + H_];
      bnx[s][q] = bih[j + 2*H_];
      bnh[s][q] = bhh[j + 2*H_];
    }

  float hold[2][4];
  #pragma unroll
  for (int s = 0; s < 2; ++s)
    #pragma unroll
    for (int q = 0; q < 4; ++q) hold[s][q] = 0.f;

  f16* scrg = scr + (size_t)g * (32 * 16 * 3 * 512);

  __syncthreads();

  for (int t = 0; t < T_; ++t){
    // ---- every 32 steps: x-part chunk GEMM into wave-private scratch (raw, no bias) ----
    if ((t & 31) == 0){
      #pragma unroll 1
      for (int m2 = 0; m2 < 16; ++m2){
        f32x4 acc[2][6];
        #pragma unroll
        for (int mm = 0; mm < 2; ++mm)
          #pragma unroll
          for (int c6 = 0; c6 < 6; ++c6)
            #pragma unroll
            for (int q = 0; q < 4; ++q) acc[mm][c6][q] = 0.f;
        #pragma unroll
        for (int kt = 0; kt < 8; ++kt){
          f16x8 a0 = *(const f16x8*)(x16 + ((size_t)(b0 + l16) * T_ + t + m2*2 + 0) * I_ + kt*32 + lg*8);
          f16x8 a1 = *(const f16x8*)(x16 + ((size_t)(b0 + l16) * T_ + t + m2*2 + 1) * I_ + kt*32 + lg*8);
          #pragma unroll
          for (int gate = 0; gate < 3; ++gate)
            #pragma unroll
            for (int s = 0; s < 2; ++s){
              f16x8 wf = *(const f16x8*)(Wih16 + (size_t)(gate * H_ + jw + s*16 + l16) * I_ + kt*32 + lg*8);
              acc[0][gate*2+s] = MFMA16(a0, wf, acc[0][gate*2+s]);
              acc[1][gate*2+s] = MFMA16(a1, wf, acc[1][gate*2+s]);
            }
        }
        #pragma unroll
        for (int mm = 0; mm < 2; ++mm){
          int m = m2 * 2 + mm;
          #pragma unroll
          for (int gate = 0; gate < 3; ++gate)
            #pragma unroll
            for (int s = 0; s < 2; ++s)
              #pragma unroll
              for (int q = 0; q < 4; ++q)
                scrg[(((size_t)m * 16 + rt[q]) * 3 + gate) * 512 + jw + s*16 + ct[q]] =
                    (f16)acc[mm][gate*2+s][q];
        }
      }
      asm volatile("s_waitcnt vmcnt(0)" ::: "memory");  // own stores visible to own loads below
    }

    // ---- prefetch this step's x pre-activations (wave-private scratch, L2-hot) ----
    const int tl = t & 31;
    float sx[3][2][4];
    #pragma unroll
    for (int gate = 0; gate < 3; ++gate)
      #pragma unroll
      for (int s = 0; s < 2; ++s)
        #pragma unroll
        for (int q = 0; q < 4; ++q)
          sx[gate][s][q] = (float)scrg[(((size_t)tl * 16 + rt[q]) * 3 + gate) * 512 + jw + s*16 + ct[q]];

    // ---- h-GEMM: 96 MFMAs from register-resident W_hh ----
    const int cur = t & 1;
    f32x4 hacc[6];
    #pragma unroll
    for (int c6 = 0; c6 < 6; ++c6)
      #pragma unroll
      for (int q = 0; q < 4; ++q) hacc[c6][q] = 0.f;
    #pragma unroll
    for (int kt = 0; kt < 16; ++kt){
      f16x8 a = *(const f16x8*)&hl[cur][l16][kt * 32 + lg * 8];
      #pragma unroll
      for (int gate = 0; gate < 3; ++gate)
        #pragma unroll
        for (int s = 0; s < 2; ++s)
          hacc[gate*2+s] = MFMA16(a, wh[gate][s][kt], hacc[gate*2+s]);
    }

    // ---- epilogue: gates + state update; write h' to LDS[nxt] + hs ----
    #pragma unroll
    for (int s = 0; s < 2; ++s)
      #pragma unroll
      for (int q = 0; q < 4; ++q){
        float r  = sigm(hacc[0*2+s][q] + sx[0][s][q] + brc[s][q]);
        float z  = sigm(hacc[1*2+s][q] + sx[1][s][q] + bzc[s][q]);
        float nn = tanh_f(sx[2][s][q] + bnx[s][q] + r * (hacc[2*2+s][q] + bnh[s][q]));
        float h  = (1.f - z) * nn + z * hold[s][q];
        hold[s][q] = h;
        int row = rt[q], col = jw + s*16 + ct[q];
        f16 hh = (f16)h;
        hl[cur ^ 1][row][col] = hh;
        hs[((size_t)t * B_ + b0 + row) * H_ + col] = hh;
      }
    __syncthreads();
  }
}

// ---------------- fused attention: scores MFMA + e-transpose + vectorized weighted sum ----------
__global__ __launch_bounds__(256, 1) void k_att(const f16* __restrict__ hs,
    const f16* __restrict__ Wat2, const int* __restrict__ rtab, const int* __restrict__ ctab,
    float* __restrict__ out){
  const int b  = blockIdx.x >> 1;
  const int jh = blockIdx.x & 1;
  const int tid = threadIdx.x, wv = tid >> 6, lane = tid & 63, l16 = lane & 15, lg = lane >> 4;
  const int jb = jh * 256 + wv * 64;

  __shared__ __align__(16) float etile[4][16 * TP];

  int rt[4], ct[4];
  #pragma unroll
  for (int q = 0; q < 4; ++q){ rt[q] = rtab[lane*4+q]; ct[q] = ctab[lane*4+q]; }

  f16x8 ones;
  #pragma unroll
  for (int e = 0; e < 8; ++e) ones[e] = (f16)0.f;
  if (lg == 0) ones[0] = (f16)1.f;

  float num[4][4], den[4][4];
  #pragma unroll
  for (int nt = 0; nt < 4; ++nt)
    #pragma unroll
    for (int k = 0; k < 4; ++k){ num[nt][k] = 0.f; den[nt][k] = 0.f; }

  for (int tt = 0; tt < 32; ++tt){
    f16x8 a[16];
    const f16* ar = hs + ((size_t)(tt*16 + l16) * B_ + b) * H_ + lg * 8;
    #pragma unroll
    for (int kt = 0; kt < 16; ++kt) a[kt] = *(const f16x8*)(ar + kt * 32);

    #pragma unroll
    for (int nt = 0; nt < 4; ++nt){
      f32x4 acc;
      #pragma unroll
      for (int q = 0; q < 4; ++q) acc[q] = 0.f;
      const f16* wr = Wat2 + (size_t)(jb + nt*16 + l16) * KA2 + lg * 8;
      #pragma unroll
      for (int kt = 0; kt < 16; ++kt){
        f16x8 bf = *(const f16x8*)(wr + kt * 32);
        acc = MFMA16(a[kt], bf, acc);
      }
      { f16x8 bf = *(const f16x8*)(wr + 512); acc = MFMA16(ones, bf, acc); }

      #pragma unroll
      for (int q = 0; q < 4; ++q)
        etile[wv][rt[q] * TP + ct[q]] = fast_exp(tanh_f(acc[q]));
      asm volatile("s_waitcnt lgkmcnt(0)" ::: "memory");
      f32x4 ev = *(const f32x4*)&etile[wv][(lane>>2) * TP + (lane & 3) * 4];
      const f16* hp = hs + ((size_t)(tt*16 + (lane>>2)) * B_ + b) * H_ + jb + nt*16 + (lane&3)*4;
      f16x4 hv = *(const f16x4*)hp;
      #pragma unroll
      for (int k = 0; k < 4; ++k){
        num[nt][k] = fmaf(ev[k], (float)hv[k], num[nt][k]);
        den[nt][k] += ev[k];
      }
    }
  }

  #pragma unroll
  for (int nt = 0; nt < 4; ++nt){
    #pragma unroll
    for (int k = 0; k < 4; ++k){
      float n = num[nt][k], d = den[nt][k];
      #pragma unroll
      for (int m = 4; m <= 32; m <<= 1){ n += __shfl_xor(n, m, 64); d += __shfl_xor(d, m, 64); }
      if (lane < 4) out[(size_t)b * H_ + jb + nt*16 + lane*4 + k] = n / d;
    }
  }
}

extern "C" void kernel_launch(void* const* d_in, const int* in_sizes, int n_in,
                              void* d_out, int out_size, void* d_ws, size_t ws_size,
                              hipStream_t stream){
  (void)in_sizes; (void)n_in; (void)out_size;
  const float* x    = (const float*)d_in[0];
  const float* Wih  = (const float*)d_in[1];
  const float* Whh  = (const float*)d_in[2];
  const float* bih  = (const float*)d_in[3];
  const float* bhh  = (const float*)d_in[4];
  const float* Watt = (const float*)d_in[5];
  const float* batt = (const float*)d_in[6];

  char* ws = (char*)d_ws;
  // layout (bytes):
  //   hs   : [T][B][H] f16           @ 0            (67,108,864)
  //   x16  : [B][T][I] f16           @ 67,108,864   (33,554,432)
  //   Wih16: [1536][256] f16         @ 100,663,296  (786,432)
  //   Wat2 : [512][544] f16          @ 101,449,728  (557,056)
  //   rtab : int[256]                @ 102,006,784  (1,024)
  //   ctab : int[256]                @ 102,007,808  (1,024)
  //   scr  : [8][32][16][3][512] f16 @ 102,008,832  (12,582,912)
  const size_t OFF_HS  = 0ull;
  const size_t OFF_X16 = 67108864ull;
  const size_t OFF_WIH = 100663296ull;
  const size_t OFF_WAT = 101449728ull;
  const size_t OFF_RT  = 102006784ull;
  const size_t OFF_CT  = 102007808ull;
  const size_t OFF_SCR = 102008832ull;
  const size_t NEED    = 114591744ull;
  if (ws_size < NEED) return;

  f16* hs    = (f16*)(ws + OFF_HS);
  f16* x16   = (f16*)(ws + OFF_X16);
  f16* Wih16 = (f16*)(ws + OFF_WIH);
  f16* Wat2  = (f16*)(ws + OFF_WAT);
  int* rtab  = (int*)(ws + OFF_RT);
  int* ctab  = (int*)(ws + OFF_CT);
  f16* scr   = (f16*)(ws + OFF_SCR);

  k_prep <<<2048, 256, 0, stream>>>(x, Wih, Watt, batt, x16, Wih16, Wat2);
  k_probe<<<1,    64,  0, stream>>>(rtab, ctab);
  k_rec  <<<8,   1024, 0, stream>>>(x16, Whh, bih, bhh, Wih16, rtab, ctab, scr, hs);
  k_att  <<<256,  256, 0, stream>>>(hs, Wat2, rtab, ctab, (float*)d_out);
}

// Round 13
// 3738.829 us; speedup vs baseline: 8.1959x; 8.1959x over previous
//
#include <hip/hip_runtime.h>
#include <hip/hip_bf16.h>
#include <hip/hip_fp16.h>

typedef _Float16 f16;
typedef __attribute__((ext_vector_type(4))) _Float16 f16x4;
typedef __attribute__((ext_vector_type(8))) _Float16 f16x8;
typedef __attribute__((ext_vector_type(4))) float f32x4;

#define T_ 512
#define B_ 128
#define I_ 256
#define H_ 512
#define G3_ 1536
#define KC2 832     // Wc2 cols: [0,512) W_hh | 512 b_hh | 0 | [544,800) W_ih | 800 b_ih | 0
#define XOFF 544
#define KA2 544     // Wat2 cols: [0,512) W_att | 512 b_att | 0
#define NKT 26
#define NFRAG (NKT*3)   // 78 B-fragments per (c)-slice
#define TP 20

#define MFMA16(a,b,c) __builtin_amdgcn_mfma_f32_16x16x32_f16((a),(b),(c),0,0,0)

__device__ __forceinline__ float fast_exp(float x){
  return __builtin_amdgcn_exp2f(x * 1.4426950408889634f);
}
__device__ __forceinline__ float sigm(float x){
  return __builtin_amdgcn_rcpf(1.f + fast_exp(-x));
}
__device__ __forceinline__ float tanh_f(float x){
  return 1.f - 2.f * __builtin_amdgcn_rcpf(1.f + fast_exp(2.f * x));
}

// ---------------- prep: Wc2 (folded biases) + Wat2 + x16 ----------------
__global__ void k_prep(const float* __restrict__ x, const float* __restrict__ Wih,
                       const float* __restrict__ Whh,
                       const float* __restrict__ bih, const float* __restrict__ bhh,
                       const float* __restrict__ Watt, const float* __restrict__ batt,
                       f16* __restrict__ Wc2, f16* __restrict__ Wat2, f16* __restrict__ x16){
  const int n1 = G3_ * KC2;
  const int n2 = H_ * KA2;
  const int n3 = B_ * T_ * I_;
  const int tot = n1 + n2 + n3;
  for (int i = blockIdx.x * blockDim.x + threadIdx.x; i < tot; i += gridDim.x * blockDim.x){
    if (i < n1){
      int r = i / KC2, k = i % KC2;
      float v;
      if      (k <  H_)   v = Whh[r * H_ + k];
      else if (k == H_)   v = bhh[r];
      else if (k <  XOFF) v = 0.f;
      else if (k <  800)  v = Wih[r * I_ + (k - XOFF)];
      else if (k == 800)  v = bih[r];
      else                v = 0.f;
      Wc2[i] = (f16)v;
    } else if (i < n1 + n2){
      int j = i - n1; int r = j / KA2, k = j % KA2;
      float v = (k < H_) ? Watt[r * H_ + k] : (k == H_ ? batt[r] : 0.f);
      Wat2[j] = (f16)v;
    } else {
      int j = i - n1 - n2;
      x16[j] = (f16)x[j];
    }
  }
}

// ---------------- relayout: fragment-linear weights, WlinG[c][f][lane][8] ----------------
__global__ void k_relayout(const f16* __restrict__ Wc2, f16* __restrict__ WlinG){
  int i = blockIdx.x * blockDim.x + threadIdx.x;       // 32*78*64 = 159,744 chunks of 16B
  if (i >= 32 * NFRAG * 64) return;
  int c    = i / (NFRAG * 64);
  int rem  = i - c * (NFRAG * 64);
  int f    = rem >> 6;
  int lane = rem & 63;
  int l16 = lane & 15, lg = lane >> 4;
  int kt = f / 3, gi = f - 3 * kt;
  const f16* src = Wc2 + (size_t)(gi * H_ + c * 16 + l16) * KC2 + kt * 32 + lg * 8;
  *(f16x8*)(WlinG + (size_t)i * 8) = *(const f16x8*)src;
}

// ---------------- probe: (lane,reg)->(row,col) D mapping ----------------
__global__ void k_probe(int* __restrict__ rtab, int* __restrict__ ctab){
  __shared__ __align__(16) f16 A[16][32];
  __shared__ __align__(16) f16 BT[16][32];
  const int l = threadIdx.x, l16 = l & 15, lg = l >> 4;
  for (int i = l; i < 512; i += 64){ ((f16*)A)[i] = (f16)0.f; ((f16*)BT)[i] = (f16)0.f; }
  __syncthreads();
  if (l < 16){
    A[l][0]  = (f16)(float)(16 * l);
    A[l][1]  = (f16)1.f;
    BT[l][0] = (f16)1.f;
    BT[l][1] = (f16)(float)l;
  }
  __syncthreads();
  f16x8 a = *(const f16x8*)&A[l16][lg * 8];
  f16x8 b = *(const f16x8*)&BT[l16][lg * 8];
  f32x4 z; z[0]=0.f; z[1]=0.f; z[2]=0.f; z[3]=0.f;
  f32x4 d = MFMA16(a, b, z);
  #pragma unroll
  for (int q = 0; q < 4; ++q){
    int code = (int)(d[q] + 0.5f);
    rtab[l * 4 + q] = code >> 4;
    ctab[l * 4 + q] = code & 15;
  }
}

// ---------------- one recurrence step: kernel boundary = the global barrier ----------------
// 256 WGs x 64 thr. WG (g=bid&7, c=bid>>3): batch rows [16g,16g+16), h-cols [16c,16c+16).
// Reads hin (h(t-1)), writes hout (h(t)) + hs[t]. Stream order guarantees visibility.
__global__ __launch_bounds__(64) void k_step(int t, const f16* __restrict__ x16,
    const f16* __restrict__ WlinG, const int* __restrict__ rtab, const int* __restrict__ ctab,
    const f16* __restrict__ hin, f16* __restrict__ hout, f16* __restrict__ hs){
  const int bid = blockIdx.x;
  const int g = bid & 7, c = bid >> 3;
  const int b0 = g * 16, j0 = c * 16;
  const int lane = threadIdx.x, l16 = lane & 15, lg = lane >> 4;

  __shared__ __align__(16) f16 ttile[16 * TP];

  int rt[4], ct[4];
  #pragma unroll
  for (int q = 0; q < 4; ++q){ rt[q] = rtab[lane*4+q]; ct[q] = ctab[lane*4+q]; }

  f16x8 ones;
  #pragma unroll
  for (int e = 0; e < 8; ++e) ones[e] = (f16)0.f;
  if (lg == 0) ones[0] = (f16)1.f;   // bias k-slot

  // previous h for this lane's 4 output slots (z-gate blend)
  float hold[4];
  #pragma unroll
  for (int q = 0; q < 4; ++q)
    hold[q] = (float)hin[(size_t)(b0 + rt[q]) * H_ + j0 + ct[q]];

  const f16* wbase = WlinG + ((size_t)c * NFRAG * 64 + lane) * 8;  // + f*512 per fragment
  const f16* hrow  = hin + (size_t)(b0 + l16) * H_ + lg * 8;
  const f16* xrow  = x16 + ((size_t)(b0 + l16) * T_ + t) * I_ + lg * 8;

  f32x4 aR, aZ, aNh, aNx;
  #pragma unroll
  for (int q = 0; q < 4; ++q){ aR[q]=0.f; aZ[q]=0.f; aNh[q]=0.f; aNx[q]=0.f; }

  // h-part: k-tiles 0..15
  #pragma unroll 4
  for (int kt = 0; kt < 16; ++kt){
    f16x8 a  = *(const f16x8*)(hrow + kt * 32);
    f16x8 w0 = *(const f16x8*)(wbase + (size_t)(kt*3+0) * 512);
    f16x8 w1 = *(const f16x8*)(wbase + (size_t)(kt*3+1) * 512);
    f16x8 w2 = *(const f16x8*)(wbase + (size_t)(kt*3+2) * 512);
    aR  = MFMA16(a, w0, aR);
    aZ  = MFMA16(a, w1, aZ);
    aNh = MFMA16(a, w2, aNh);
  }
  // h-bias tile (k-tile 16)
  {
    f16x8 w0 = *(const f16x8*)(wbase + (size_t)(16*3+0) * 512);
    f16x8 w1 = *(const f16x8*)(wbase + (size_t)(16*3+1) * 512);
    f16x8 w2 = *(const f16x8*)(wbase + (size_t)(16*3+2) * 512);
    aR  = MFMA16(ones, w0, aR);
    aZ  = MFMA16(ones, w1, aZ);
    aNh = MFMA16(ones, w2, aNh);
  }
  // x-part: k-tiles 17..24
  #pragma unroll 4
  for (int kx = 0; kx < 8; ++kx){
    int f = (17 + kx) * 3;
    f16x8 a  = *(const f16x8*)(xrow + kx * 32);
    f16x8 w0 = *(const f16x8*)(wbase + (size_t)(f+0) * 512);
    f16x8 w1 = *(const f16x8*)(wbase + (size_t)(f+1) * 512);
    f16x8 w2 = *(const f16x8*)(wbase + (size_t)(f+2) * 512);
    aR  = MFMA16(a, w0, aR);
    aZ  = MFMA16(a, w1, aZ);
    aNx = MFMA16(a, w2, aNx);
  }
  // x-bias tile (k-tile 25)
  {
    f16x8 w0 = *(const f16x8*)(wbase + (size_t)(25*3+0) * 512);
    f16x8 w1 = *(const f16x8*)(wbase + (size_t)(25*3+1) * 512);
    f16x8 w2 = *(const f16x8*)(wbase + (size_t)(25*3+2) * 512);
    aR  = MFMA16(ones, w0, aR);
    aZ  = MFMA16(ones, w1, aZ);
    aNx = MFMA16(ones, w2, aNx);
  }

  // epilogue: gates -> h; LDS transpose for coalesced 8B stores (r8-proven pattern)
  #pragma unroll
  for (int q = 0; q < 4; ++q){
    float r  = sigm(aR[q]);
    float z  = sigm(aZ[q]);
    float nn = tanh_f(aNx[q] + r * aNh[q]);
    float h  = (1.f - z) * nn + z * hold[q];
    ttile[rt[q] * TP + ct[q]] = (f16)h;
  }
  asm volatile("s_waitcnt lgkmcnt(0)" ::: "memory");
  const int rr = lane >> 2, c4 = (lane & 3) * 4;
  f16x4 tv = *(const f16x4*)&ttile[rr * TP + c4];
  unsigned long long pk;
  __builtin_memcpy(&pk, &tv, 8);

  *(unsigned long long*)(hout + (size_t)(b0 + rr) * H_ + j0 + c4) = pk;
  *(unsigned long long*)(hs + ((size_t)t * B_ + b0 + rr) * H_ + j0 + c4) = pk;
}

// ---------------- fused attention (r8-proven) ----------------
__global__ __launch_bounds__(256, 1) void k_att(const f16* __restrict__ hs,
    const f16* __restrict__ Wat2, const int* __restrict__ rtab, const int* __restrict__ ctab,
    float* __restrict__ out){
  const int b  = blockIdx.x >> 1;
  const int jh = blockIdx.x & 1;
  const int tid = threadIdx.x, wv = tid >> 6, lane = tid & 63, l16 = lane & 15, lg = lane >> 4;
  const int jb = jh * 256 + wv * 64;

  __shared__ __align__(16) float etile[4][16 * TP];

  int rt[4], ct[4];
  #pragma unroll
  for (int q = 0; q < 4; ++q){ rt[q] = rtab[lane*4+q]; ct[q] = ctab[lane*4+q]; }

  f16x8 ones;
  #pragma unroll
  for (int e = 0; e < 8; ++e) ones[e] = (f16)0.f;
  if (lg == 0) ones[0] = (f16)1.f;

  float num[4][4], den[4][4];
  #pragma unroll
  for (int nt = 0; nt < 4; ++nt)
    #pragma unroll
    for (int k = 0; k < 4; ++k){ num[nt][k] = 0.f; den[nt][k] = 0.f; }

  for (int tt = 0; tt < 32; ++tt){
    f16x8 a[16];
    const f16* ar = hs + ((size_t)(tt*16 + l16) * B_ + b) * H_ + lg * 8;
    #pragma unroll
    for (int kt = 0; kt < 16; ++kt) a[kt] = *(const f16x8*)(ar + kt * 32);

    #pragma unroll
    for (int nt = 0; nt < 4; ++nt){
      f32x4 acc;
      #pragma unroll
      for (int q = 0; q < 4; ++q) acc[q] = 0.f;
      const f16* wr = Wat2 + (size_t)(jb + nt*16 + l16) * KA2 + lg * 8;
      #pragma unroll
      for (int kt = 0; kt < 16; ++kt){
        f16x8 bf = *(const f16x8*)(wr + kt * 32);
        acc = MFMA16(a[kt], bf, acc);
      }
      { f16x8 bf = *(const f16x8*)(wr + 512); acc = MFMA16(ones, bf, acc); }

      #pragma unroll
      for (int q = 0; q < 4; ++q)
        etile[wv][rt[q] * TP + ct[q]] = fast_exp(tanh_f(acc[q]));
      asm volatile("s_waitcnt lgkmcnt(0)" ::: "memory");
      f32x4 ev = *(const f32x4*)&etile[wv][(lane>>2) * TP + (lane & 3) * 4];
      const f16* hp = hs + ((size_t)(tt*16 + (lane>>2)) * B_ + b) * H_ + jb + nt*16 + (lane&3)*4;
      f16x4 hv = *(const f16x4*)hp;
      #pragma unroll
      for (int k = 0; k < 4; ++k){
        num[nt][k] = fmaf(ev[k], (float)hv[k], num[nt][k]);
        den[nt][k] += ev[k];
      }
    }
  }

  #pragma unroll
  for (int nt = 0; nt < 4; ++nt){
    #pragma unroll
    for (int k = 0; k < 4; ++k){
      float n = num[nt][k], d = den[nt][k];
      #pragma unroll
      for (int m = 4; m <= 32; m <<= 1){ n += __shfl_xor(n, m, 64); d += __shfl_xor(d, m, 64); }
      if (lane < 4) out[(size_t)b * H_ + jb + nt*16 + lane*4 + k] = n / d;
    }
  }
}

extern "C" void kernel_launch(void* const* d_in, const int* in_sizes, int n_in,
                              void* d_out, int out_size, void* d_ws, size_t ws_size,
                              hipStream_t stream){
  (void)in_sizes; (void)n_in; (void)out_size;
  const float* x    = (const float*)d_in[0];
  const float* Wih  = (const float*)d_in[1];
  const float* Whh  = (const float*)d_in[2];
  const float* bih  = (const float*)d_in[3];
  const float* bhh  = (const float*)d_in[4];
  const float* Watt = (const float*)d_in[5];
  const float* batt = (const float*)d_in[6];

  char* ws = (char*)d_ws;
  // layout (bytes):
  //   hs   : [T][B][H] f16            @ 0            (67,108,864)
  //   x16  : [B][T][I] f16            @ 67,108,864   (33,554,432)
  //   Wc2  : [1536][832] f16          @ 100,663,296  (2,555,904)
  //   WlinG: [32][78][64][8] f16      @ 103,219,200  (2,555,904)
  //   Wat2 : [512][544] f16           @ 105,775,104  (557,056)
  //   rtab : int[256]                 @ 106,332,160  (1,024)
  //   ctab : int[256]                 @ 106,333,184  (1,024)
  //   hA   : [128][512] f16           @ 106,334,208  (131,072)
  //   hB   : [128][512] f16           @ 106,465,280  (131,072)
  const size_t OFF_HS  = 0ull;
  const size_t OFF_X16 = 67108864ull;
  const size_t OFF_WC2 = 100663296ull;
  const size_t OFF_WLG = 103219200ull;
  const size_t OFF_WAT = 105775104ull;
  const size_t OFF_RT  = 106332160ull;
  const size_t OFF_CT  = 106333184ull;
  const size_t OFF_HA  = 106334208ull;
  const size_t OFF_HB  = 106465280ull;
  const size_t NEED    = 106596352ull;
  if (ws_size < NEED) return;

  f16* hs    = (f16*)(ws + OFF_HS);
  f16* x16   = (f16*)(ws + OFF_X16);
  f16* Wc2   = (f16*)(ws + OFF_WC2);
  f16* WlinG = (f16*)(ws + OFF_WLG);
  f16* Wat2  = (f16*)(ws + OFF_WAT);
  int* rtab  = (int*)(ws + OFF_RT);
  int* ctab  = (int*)(ws + OFF_CT);
  f16* hA    = (f16*)(ws + OFF_HA);
  f16* hB    = (f16*)(ws + OFF_HB);

  // h(-1) = 0 every launch (hA gets overwritten by step 511 of the previous replay)
  hipMemsetAsync(ws + OFF_HA, 0, 131072, stream);

  k_prep    <<<2048, 256, 0, stream>>>(x, Wih, Whh, bih, bhh, Watt, batt, Wc2, Wat2, x16);
  k_relayout<<<624,  256, 0, stream>>>(Wc2, WlinG);
  k_probe   <<<1,    64,  0, stream>>>(rtab, ctab);

  for (int t = 0; t < T_; ++t){
    const f16* hin = (t & 1) ? hB : hA;
    f16*       hout = (t & 1) ? hA : hB;
    k_step<<<256, 64, 0, stream>>>(t, x16, WlinG, rtab, ctab, hin, hout, hs);
  }

  k_att<<<256, 256, 0, stream>>>(hs, Wat2, rtab, ctab, (float*)d_out);
}

// Round 14
// 2247.485 us; speedup vs baseline: 13.6344x; 1.6636x over previous
//
#include <hip/hip_runtime.h>
#include <hip/hip_bf16.h>
#include <hip/hip_fp16.h>

typedef _Float16 f16;
typedef __attribute__((ext_vector_type(4))) _Float16 f16x4;
typedef __attribute__((ext_vector_type(8))) _Float16 f16x8;
typedef __attribute__((ext_vector_type(4))) float f32x4;

#define T_ 512
#define B_ 128
#define I_ 256
#define H_ 512
#define G3_ 1536
#define KC2 832     // Wc2 cols: [0,512) W_hh | 512 b_hh | 0 | [544,800) W_ih | 800 b_ih | 0
#define XOFF 544
#define KA2 544     // Wat2 cols: [0,512) W_att | 512 b_att | 0
#define NKT 26
#define NFRAG (NKT*3)   // 78 B-fragments per c-slice
#define TP 20

#define MFMA16(a,b,c) __builtin_amdgcn_mfma_f32_16x16x32_f16((a),(b),(c),0,0,0)

__device__ __forceinline__ float fast_exp(float x){
  return __builtin_amdgcn_exp2f(x * 1.4426950408889634f);
}
__device__ __forceinline__ float sigm(float x){
  return __builtin_amdgcn_rcpf(1.f + fast_exp(-x));
}
__device__ __forceinline__ float tanh_f(float x){
  return 1.f - 2.f * __builtin_amdgcn_rcpf(1.f + fast_exp(2.f * x));
}

// ---------------- prep: Wc2 (folded biases) + Wat2 + x16 ----------------
__global__ void k_prep(const float* __restrict__ x, const float* __restrict__ Wih,
                       const float* __restrict__ Whh,
                       const float* __restrict__ bih, const float* __restrict__ bhh,
                       const float* __restrict__ Watt, const float* __restrict__ batt,
                       f16* __restrict__ Wc2, f16* __restrict__ Wat2, f16* __restrict__ x16){
  const int n1 = G3_ * KC2;
  const int n2 = H_ * KA2;
  const int n3 = B_ * T_ * I_;
  const int tot = n1 + n2 + n3;
  for (int i = blockIdx.x * blockDim.x + threadIdx.x; i < tot; i += gridDim.x * blockDim.x){
    if (i < n1){
      int r = i / KC2, k = i % KC2;
      float v;
      if      (k <  H_)   v = Whh[r * H_ + k];
      else if (k == H_)   v = bhh[r];
      else if (k <  XOFF) v = 0.f;
      else if (k <  800)  v = Wih[r * I_ + (k - XOFF)];
      else if (k == 800)  v = bih[r];
      else                v = 0.f;
      Wc2[i] = (f16)v;
    } else if (i < n1 + n2){
      int j = i - n1; int r = j / KA2, k = j % KA2;
      float v = (k < H_) ? Watt[r * H_ + k] : (k == H_ ? batt[r] : 0.f);
      Wat2[j] = (f16)v;
    } else {
      int j = i - n1 - n2;
      x16[j] = (f16)x[j];
    }
  }
}

// ---------------- relayout: fragment-linear weights, WlinG[c][f][lane][8] ----------------
__global__ void k_relayout(const f16* __restrict__ Wc2, f16* __restrict__ WlinG){
  int i = blockIdx.x * blockDim.x + threadIdx.x;       // 32*78*64 chunks of 16B
  if (i >= 32 * NFRAG * 64) return;
  int c    = i / (NFRAG * 64);
  int rem  = i - c * (NFRAG * 64);
  int f    = rem >> 6;
  int lane = rem & 63;
  int l16 = lane & 15, lg = lane >> 4;
  int kt = f / 3, gi = f - 3 * kt;
  const f16* src = Wc2 + (size_t)(gi * H_ + c * 16 + l16) * KC2 + kt * 32 + lg * 8;
  *(f16x8*)(WlinG + (size_t)i * 8) = *(const f16x8*)src;
}

// ---------------- probe: (lane,reg)->(row,col) D mapping ----------------
__global__ void k_probe(int* __restrict__ rtab, int* __restrict__ ctab){
  __shared__ __align__(16) f16 A[16][32];
  __shared__ __align__(16) f16 BT[16][32];
  const int l = threadIdx.x, l16 = l & 15, lg = l >> 4;
  for (int i = l; i < 512; i += 64){ ((f16*)A)[i] = (f16)0.f; ((f16*)BT)[i] = (f16)0.f; }
  __syncthreads();
  if (l < 16){
    A[l][0]  = (f16)(float)(16 * l);
    A[l][1]  = (f16)1.f;
    BT[l][0] = (f16)1.f;
    BT[l][1] = (f16)(float)l;
  }
  __syncthreads();
  f16x8 a = *(const f16x8*)&A[l16][lg * 8];
  f16x8 b = *(const f16x8*)&BT[l16][lg * 8];
  f32x4 z; z[0]=0.f; z[1]=0.f; z[2]=0.f; z[3]=0.f;
  f32x4 d = MFMA16(a, b, z);
  #pragma unroll
  for (int q = 0; q < 4; ++q){
    int code = (int)(d[q] + 0.5f);
    rtab[l * 4 + q] = code >> 4;
    ctab[l * 4 + q] = code & 15;
  }
}

// ---------------- x-part precompute for a 32-step chunk -------------------------------------
// gx'[tl][g][c][gate][lane*4+q] = (x(t0+tl) @ Wih^T + b_ih (+ b_hh for R,Z)) at D-slot (lane,q)
// of the SAME tile geometry k_step uses -> slot-aligned, mapping cancels, no transpose needed.
__global__ __launch_bounds__(256, 1) void k_xg(int t0, const f16* __restrict__ x16,
    const f16* __restrict__ WlinG, f16* __restrict__ gxl){
  const int tid = threadIdx.x, wv = tid >> 6, lane = tid & 63, l16 = lane & 15, lg = lane >> 4;
  const int wid = blockIdx.x * 4 + wv;     // 0..1023
  const int tq = wid & 3;
  const int c  = (wid >> 2) & 31;
  const int g  = wid >> 7;
  const int b0 = g * 16;

  f16x8 ones;
  #pragma unroll
  for (int e = 0; e < 8; ++e) ones[e] = (f16)0.f;
  if (lg == 0) ones[0] = (f16)1.f;

  // preload B-frags: per gate, 8 x-tiles + b_ih tile + (R,Z) b_hh tile
  const f16* wb = WlinG + ((size_t)c * NFRAG * 64 + lane) * 8;
  f16x8 bw[3][10];
  #pragma unroll
  for (int gate = 0; gate < 3; ++gate){
    #pragma unroll
    for (int kx = 0; kx < 8; ++kx)
      bw[gate][kx] = *(const f16x8*)(wb + (size_t)((17 + kx) * 3 + gate) * 512);
    bw[gate][8] = *(const f16x8*)(wb + (size_t)(25 * 3 + gate) * 512);   // b_ih
    if (gate < 2)
      bw[gate][9] = *(const f16x8*)(wb + (size_t)(16 * 3 + gate) * 512); // b_hh (R,Z only)
  }

  for (int tl = tq * 8; tl < tq * 8 + 8; ++tl){
    const int t = t0 + tl;
    f16x8 a[8];
    const f16* xrow = x16 + ((size_t)(b0 + l16) * T_ + t) * I_ + lg * 8;
    #pragma unroll
    for (int kx = 0; kx < 8; ++kx) a[kx] = *(const f16x8*)(xrow + kx * 32);

    #pragma unroll
    for (int gate = 0; gate < 3; ++gate){
      f32x4 acc;
      #pragma unroll
      for (int q = 0; q < 4; ++q) acc[q] = 0.f;
      #pragma unroll
      for (int kx = 0; kx < 8; ++kx) acc = MFMA16(a[kx], bw[gate][kx], acc);
      acc = MFMA16(ones, bw[gate][8], acc);
      if (gate < 2) acc = MFMA16(ones, bw[gate][9], acc);
      f16x4 o;
      #pragma unroll
      for (int q = 0; q < 4; ++q) o[q] = (f16)acc[q];
      *(f16x4*)(gxl + ((((size_t)tl * 8 + g) * 32 + c) * 3 + gate) * 256 + lane * 4) = o;
    }
  }
}

// ---------------- one recurrence step (h-part only), 2-wave k-split -------------------------
// 256 WGs x 128 thr. WG (g=bid&7, c=bid>>3). Wave w does k-tiles 8w..8w+7 for all 3 gates;
// wave 1 posts partials via LDS; wave 0 combines + gates + stores. Kernel boundary = barrier.
__global__ __launch_bounds__(128) void k_step(int t, const f16* __restrict__ gx,
    const f16* __restrict__ WlinG, const float* __restrict__ bhh,
    const int* __restrict__ rtab, const int* __restrict__ ctab,
    const f16* __restrict__ hin, f16* __restrict__ hout, f16* __restrict__ hs){
  const int bid = blockIdx.x;
  const int g = bid & 7, c = bid >> 3;
  const int b0 = g * 16, j0 = c * 16;
  const int tid = threadIdx.x, w = tid >> 6, lane = tid & 63, l16 = lane & 15, lg = lane >> 4;

  __shared__ __align__(16) float part[64][13];
  __shared__ __align__(16) f16 ttile[16 * TP];

  int rt[4], ct[4];
  #pragma unroll
  for (int q = 0; q < 4; ++q){ rt[q] = rtab[lane*4+q]; ct[q] = ctab[lane*4+q]; }

  // wave 0: issue epilogue operands early (overlap with MFMA loop)
  f16x4 gR, gZ, gN;
  float hold[4], bnhv[4];
  #pragma unroll
  for (int q = 0; q < 4; ++q){ hold[q] = 0.f; bnhv[q] = 0.f; }
  if (w == 0){
    const f16* gp = gx + ((((size_t)(t & 31)) * 8 + g) * 32 + c) * 3 * 256;
    gR = *(const f16x4*)(gp + 0 * 256 + lane * 4);
    gZ = *(const f16x4*)(gp + 1 * 256 + lane * 4);
    gN = *(const f16x4*)(gp + 2 * 256 + lane * 4);
    #pragma unroll
    for (int q = 0; q < 4; ++q){
      hold[q] = (float)hin[(size_t)(b0 + rt[q]) * H_ + j0 + ct[q]];
      bnhv[q] = bhh[2 * H_ + j0 + ct[q]];
    }
  }

  const f16* wbase = WlinG + ((size_t)c * NFRAG * 64 + lane) * 8;
  const f16* hrow  = hin + (size_t)(b0 + l16) * H_ + lg * 8;

  f32x4 aR, aZ, aNh;
  #pragma unroll
  for (int q = 0; q < 4; ++q){ aR[q] = 0.f; aZ[q] = 0.f; aNh[q] = 0.f; }

  const int k0 = w * 8;
  #pragma unroll
  for (int kt = 0; kt < 8; ++kt){
    const int kk = k0 + kt;
    f16x8 a  = *(const f16x8*)(hrow + kk * 32);
    f16x8 w0 = *(const f16x8*)(wbase + (size_t)(kk*3+0) * 512);
    f16x8 w1 = *(const f16x8*)(wbase + (size_t)(kk*3+1) * 512);
    f16x8 w2 = *(const f16x8*)(wbase + (size_t)(kk*3+2) * 512);
    aR  = MFMA16(a, w0, aR);
    aZ  = MFMA16(a, w1, aZ);
    aNh = MFMA16(a, w2, aNh);
  }

  if (w == 1){
    #pragma unroll
    for (int q = 0; q < 4; ++q){
      part[lane][q]     = aR[q];
      part[lane][4 + q] = aZ[q];
      part[lane][8 + q] = aNh[q];
    }
  }
  __syncthreads();

  if (w == 0){
    #pragma unroll
    for (int q = 0; q < 4; ++q){
      float R  = aR[q]  + part[lane][q]     + (float)gR[q];
      float Z  = aZ[q]  + part[lane][4 + q] + (float)gZ[q];
      float Nh = aNh[q] + part[lane][8 + q] + bnhv[q];
      float r  = sigm(R);
      float z  = sigm(Z);
      float nn = tanh_f((float)gN[q] + r * Nh);
      float h  = (1.f - z) * nn + z * hold[q];
      ttile[rt[q] * TP + ct[q]] = (f16)h;
    }
    asm volatile("s_waitcnt lgkmcnt(0)" ::: "memory");
    const int rr = lane >> 2, c4 = (lane & 3) * 4;
    f16x4 tv = *(const f16x4*)&ttile[rr * TP + c4];
    unsigned long long pk;
    __builtin_memcpy(&pk, &tv, 8);
    *(unsigned long long*)(hout + (size_t)(b0 + rr) * H_ + j0 + c4) = pk;
    *(unsigned long long*)(hs + ((size_t)t * B_ + b0 + rr) * H_ + j0 + c4) = pk;
  }
}

// ---------------- fused attention (r13-proven) ----------------
__global__ __launch_bounds__(256, 1) void k_att(const f16* __restrict__ hs,
    const f16* __restrict__ Wat2, const int* __restrict__ rtab, const int* __restrict__ ctab,
    float* __restrict__ out){
  const int b  = blockIdx.x >> 1;
  const int jh = blockIdx.x & 1;
  const int tid = threadIdx.x, wv = tid >> 6, lane = tid & 63, l16 = lane & 15, lg = lane >> 4;
  const int jb = jh * 256 + wv * 64;

  __shared__ __align__(16) float etile[4][16 * TP];

  int rt[4], ct[4];
  #pragma unroll
  for (int q = 0; q < 4; ++q){ rt[q] = rtab[lane*4+q]; ct[q] = ctab[lane*4+q]; }

  f16x8 ones;
  #pragma unroll
  for (int e = 0; e < 8; ++e) ones[e] = (f16)0.f;
  if (lg == 0) ones[0] = (f16)1.f;

  float num[4][4], den[4][4];
  #pragma unroll
  for (int nt = 0; nt < 4; ++nt)
    #pragma unroll
    for (int k = 0; k < 4; ++k){ num[nt][k] = 0.f; den[nt][k] = 0.f; }

  for (int tt = 0; tt < 32; ++tt){
    f16x8 a[16];
    const f16* ar = hs + ((size_t)(tt*16 + l16) * B_ + b) * H_ + lg * 8;
    #pragma unroll
    for (int kt = 0; kt < 16; ++kt) a[kt] = *(const f16x8*)(ar + kt * 32);

    #pragma unroll
    for (int nt = 0; nt < 4; ++nt){
      f32x4 acc;
      #pragma unroll
      for (int q = 0; q < 4; ++q) acc[q] = 0.f;
      const f16* wr = Wat2 + (size_t)(jb + nt*16 + l16) * KA2 + lg * 8;
      #pragma unroll
      for (int kt = 0; kt < 16; ++kt){
        f16x8 bf = *(const f16x8*)(wr + kt * 32);
        acc = MFMA16(a[kt], bf, acc);
      }
      { f16x8 bf = *(const f16x8*)(wr + 512); acc = MFMA16(ones, bf, acc); }

      #pragma unroll
      for (int q = 0; q < 4; ++q)
        etile[wv][rt[q] * TP + ct[q]] = fast_exp(tanh_f(acc[q]));
      asm volatile("s_waitcnt lgkmcnt(0)" ::: "memory");
      f32x4 ev = *(const f32x4*)&etile[wv][(lane>>2) * TP + (lane & 3) * 4];
      const f16* hp = hs + ((size_t)(tt*16 + (lane>>2)) * B_ + b) * H_ + jb + nt*16 + (lane&3)*4;
      f16x4 hv = *(const f16x4*)hp;
      #pragma unroll
      for (int k = 0; k < 4; ++k){
        num[nt][k] = fmaf(ev[k], (float)hv[k], num[nt][k]);
        den[nt][k] += ev[k];
      }
    }
  }

  #pragma unroll
  for (int nt = 0; nt < 4; ++nt){
    #pragma unroll
    for (int k = 0; k < 4; ++k){
      float n = num[nt][k], d = den[nt][k];
      #pragma unroll
      for (int m = 4; m <= 32; m <<= 1){ n += __shfl_xor(n, m, 64); d += __shfl_xor(d, m, 64); }
      if (lane < 4) out[(size_t)b * H_ + jb + nt*16 + lane*4 + k] = n / d;
    }
  }
}

extern "C" void kernel_launch(void* const* d_in, const int* in_sizes, int n_in,
                              void* d_out, int out_size, void* d_ws, size_t ws_size,
                              hipStream_t stream){
  (void)in_sizes; (void)n_in; (void)out_size;
  const float* x    = (const float*)d_in[0];
  const float* Wih  = (const float*)d_in[1];
  const float* Whh  = (const float*)d_in[2];
  const float* bih  = (const float*)d_in[3];
  const float* bhh  = (const float*)d_in[4];
  const float* Watt = (const float*)d_in[5];
  const float* batt = (const float*)d_in[6];

  char* ws = (char*)d_ws;
  // layout (bytes):
  //   hs   : [T][B][H] f16            @ 0            (67,108,864)
  //   x16  : [B][T][I] f16            @ 67,108,864   (33,554,432)
  //   Wc2  : [1536][832] f16          @ 100,663,296  (2,555,904)
  //   WlinG: [32][78][64][8] f16      @ 103,219,200  (2,555,904)
  //   Wat2 : [512][544] f16           @ 105,775,104  (557,056)
  //   rtab : int[256]                 @ 106,332,160  (1,024)
  //   ctab : int[256]                 @ 106,333,184  (1,024)
  //   hA   : [128][512] f16           @ 106,334,208  (131,072)
  //   hB   : [128][512] f16           @ 106,465,280  (131,072)
  //   gx0  : [32][8][32][3][256] f16  @ 106,596,352  (12,582,912)
  //   gx1  : same                     @ 119,179,264  (12,582,912)
  const size_t OFF_HS  = 0ull;
  const size_t OFF_X16 = 67108864ull;
  const size_t OFF_WC2 = 100663296ull;
  const size_t OFF_WLG = 103219200ull;
  const size_t OFF_WAT = 105775104ull;
  const size_t OFF_RT  = 106332160ull;
  const size_t OFF_CT  = 106333184ull;
  const size_t OFF_HA  = 106334208ull;
  const size_t OFF_HB  = 106465280ull;
  const size_t OFF_GX0 = 106596352ull;
  const size_t OFF_GX1 = 119179264ull;
  const size_t NEED    = 131762176ull;   // <= 137,332,736 proven available in r4
  if (ws_size < NEED) return;

  f16* hs    = (f16*)(ws + OFF_HS);
  f16* x16   = (f16*)(ws + OFF_X16);
  f16* Wc2   = (f16*)(ws + OFF_WC2);
  f16* WlinG = (f16*)(ws + OFF_WLG);
  f16* Wat2  = (f16*)(ws + OFF_WAT);
  int* rtab  = (int*)(ws + OFF_RT);
  int* ctab  = (int*)(ws + OFF_CT);
  f16* hA    = (f16*)(ws + OFF_HA);
  f16* hB    = (f16*)(ws + OFF_HB);
  f16* gxb[2] = { (f16*)(ws + OFF_GX0), (f16*)(ws + OFF_GX1) };

  // h(-1) = 0 every launch
  hipMemsetAsync(ws + OFF_HA, 0, 131072, stream);

  k_prep    <<<2048, 256, 0, stream>>>(x, Wih, Whh, bih, bhh, Watt, batt, Wc2, Wat2, x16);
  k_relayout<<<624,  256, 0, stream>>>(Wc2, WlinG);
  k_probe   <<<1,    64,  0, stream>>>(rtab, ctab);

  k_xg<<<256, 256, 0, stream>>>(0, x16, WlinG, gxb[0]);

  for (int t = 0; t < T_; ++t){
    const f16* hin  = (t & 1) ? hB : hA;
    f16*       hout = (t & 1) ? hA : hB;
    k_step<<<256, 128, 0, stream>>>(t, gxb[(t >> 5) & 1], WlinG, bhh, rtab, ctab, hin, hout, hs);
    if ((t & 31) == 0 && t + 32 < T_)
      k_xg<<<256, 256, 0, stream>>>(t + 32, x16, WlinG, gxb[((t >> 5) + 1) & 1]);
  }

  k_att<<<256, 256, 0, stream>>>(hs, Wat2, rtab, ctab, (float*)d_out);
}

// Round 16
// 2247.199 us; speedup vs baseline: 13.6361x; 1.0001x over previous
//
#include <hip/hip_runtime.h>
#include <hip/hip_bf16.h>
#include <hip/hip_fp16.h>

typedef _Float16 f16;
typedef __attribute__((ext_vector_type(4))) _Float16 f16x4;
typedef __attribute__((ext_vector_type(8))) _Float16 f16x8;
typedef __attribute__((ext_vector_type(4))) float f32x4;

#define T_ 512
#define B_ 128
#define I_ 256
#define H_ 512
#define XOFF 544
#define KA2 544     // Wat2 cols: [0,512) W_att | 512 b_att | 0
#define NFRAG 78    // 26 k-tiles x 3 gates per c-slice
#define TP 20

#define MFMA16(a,b,c) __builtin_amdgcn_mfma_f32_16x16x32_f16((a),(b),(c),0,0,0)

__device__ __forceinline__ float fast_exp(float x){
  return __builtin_amdgcn_exp2f(x * 1.4426950408889634f);
}
__device__ __forceinline__ float sigm(float x){
  return __builtin_amdgcn_rcpf(1.f + fast_exp(-x));
}
__device__ __forceinline__ float tanh_f(float x){
  return 1.f - 2.f * __builtin_amdgcn_rcpf(1.f + fast_exp(2.f * x));
}

// ---------------- prep: x16 + Wat2 + WlinG (fragment-linear weights, direct) ----------------
// WlinG[c][f][lane][8]: f = kt*3+gate; source col k = kt*32 + lg*8 + e with the Wc2 rule:
// [0,512) W_hh | 512 b_hh | 0 | [544,800) W_ih | 800 b_ih | 0 ; row r = gate*H + c*16 + l16.
// Verified value-identical to r13/r14's Wc2 + k_relayout two-step pipeline.
__global__ void k_prep(const float* __restrict__ x, const float* __restrict__ Wih,
                       const float* __restrict__ Whh,
                       const float* __restrict__ bih, const float* __restrict__ bhh,
                       const float* __restrict__ Watt, const float* __restrict__ batt,
                       f16* __restrict__ WlinG, f16* __restrict__ Wat2, f16* __restrict__ x16){
  const int n1 = B_ * T_ * I_;
  const int n2 = H_ * KA2;
  const int n3 = 32 * NFRAG * 64 * 8;
  const int tot = n1 + n2 + n3;
  for (int i = blockIdx.x * blockDim.x + threadIdx.x; i < tot; i += gridDim.x * blockDim.x){
    if (i < n1){
      x16[i] = (f16)x[i];
    } else if (i < n1 + n2){
      int j = i - n1; int r = j / KA2, k = j % KA2;
      float v = (k < H_) ? Watt[r * H_ + k] : (k == H_ ? batt[r] : 0.f);
      Wat2[j] = (f16)v;
    } else {
      int j = i - n1 - n2;
      int chunk = j >> 3, e = j & 7;
      int c = chunk / (NFRAG * 64);
      int rem = chunk - c * (NFRAG * 64);
      int f = rem >> 6, lane = rem & 63;
      int l16 = lane & 15, lg = lane >> 4;
      int kt = f / 3, gi = f - 3 * kt;
      int r = gi * H_ + c * 16 + l16;
      int k = kt * 32 + lg * 8 + e;
      float v;
      if      (k <  H_)   v = Whh[r * H_ + k];
      else if (k == H_)   v = bhh[r];
      else if (k <  XOFF) v = 0.f;
      else if (k <  800)  v = Wih[r * I_ + (k - XOFF)];
      else if (k == 800)  v = bih[r];
      else                v = 0.f;
      WlinG[j] = (f16)v;
    }
  }
}

// ---------------- probe: (lane,reg)->(row,col) D mapping ----------------
__global__ void k_probe(int* __restrict__ rtab, int* __restrict__ ctab){
  __shared__ __align__(16) f16 A[16][32];
  __shared__ __align__(16) f16 BT[16][32];
  const int l = threadIdx.x, l16 = l & 15, lg = l >> 4;
  for (int i = l; i < 512; i += 64){ ((f16*)A)[i] = (f16)0.f; ((f16*)BT)[i] = (f16)0.f; }
  __syncthreads();
  if (l < 16){
    A[l][0]  = (f16)(float)(16 * l);
    A[l][1]  = (f16)1.f;
    BT[l][0] = (f16)1.f;
    BT[l][1] = (f16)(float)l;
  }
  __syncthreads();
  f16x8 a = *(const f16x8*)&A[l16][lg * 8];
  f16x8 b = *(const f16x8*)&BT[l16][lg * 8];
  f32x4 z; z[0]=0.f; z[1]=0.f; z[2]=0.f; z[3]=0.f;
  f32x4 d = MFMA16(a, b, z);
  #pragma unroll
  for (int q = 0; q < 4; ++q){
    int code = (int)(d[q] + 0.5f);
    rtab[l * 4 + q] = code >> 4;
    ctab[l * 4 + q] = code & 15;
  }
}

// ---------------- x-part precompute for a 32-step chunk (r14-proven) ------------------------
// gx'[tl][g][c][gate][lane*4+q] = (x(t0+tl) @ Wih^T + b_ih (+ b_hh for R,Z)) at D-slot (lane,q)
__global__ __launch_bounds__(256, 1) void k_xg(int t0, const f16* __restrict__ x16,
    const f16* __restrict__ WlinG, f16* __restrict__ gxl){
  const int tid = threadIdx.x, wv = tid >> 6, lane = tid & 63, l16 = lane & 15, lg = lane >> 4;
  const int wid = blockIdx.x * 4 + wv;     // 0..1023
  const int tq = wid & 3;
  const int c  = (wid >> 2) & 31;
  const int g  = wid >> 7;
  const int b0 = g * 16;

  f16x8 ones;
  #pragma unroll
  for (int e = 0; e < 8; ++e) ones[e] = (f16)0.f;
  if (lg == 0) ones[0] = (f16)1.f;

  const f16* wb = WlinG + ((size_t)c * NFRAG * 64 + lane) * 8;
  f16x8 bw[3][10];
  #pragma unroll
  for (int gate = 0; gate < 3; ++gate){
    #pragma unroll
    for (int kx = 0; kx < 8; ++kx)
      bw[gate][kx] = *(const f16x8*)(wb + (size_t)((17 + kx) * 3 + gate) * 512);
    bw[gate][8] = *(const f16x8*)(wb + (size_t)(25 * 3 + gate) * 512);   // b_ih
    if (gate < 2)
      bw[gate][9] = *(const f16x8*)(wb + (size_t)(16 * 3 + gate) * 512); // b_hh (R,Z only)
  }

  for (int tl = tq * 8; tl < tq * 8 + 8; ++tl){
    const int t = t0 + tl;
    f16x8 a[8];
    const f16* xrow = x16 + ((size_t)(b0 + l16) * T_ + t) * I_ + lg * 8;
    #pragma unroll
    for (int kx = 0; kx < 8; ++kx) a[kx] = *(const f16x8*)(xrow + kx * 32);

    #pragma unroll
    for (int gate = 0; gate < 3; ++gate){
      f32x4 acc;
      #pragma unroll
      for (int q = 0; q < 4; ++q) acc[q] = 0.f;
      #pragma unroll
      for (int kx = 0; kx < 8; ++kx) acc = MFMA16(a[kx], bw[gate][kx], acc);
      acc = MFMA16(ones, bw[gate][8], acc);
      if (gate < 2) acc = MFMA16(ones, bw[gate][9], acc);
      f16x4 o;
      #pragma unroll
      for (int q = 0; q < 4; ++q) o[q] = (f16)acc[q];
      *(f16x4*)(gxl + ((((size_t)tl * 8 + g) * 32 + c) * 3 + gate) * 256 + lane * 4) = o;
    }
  }
}

// ---------------- one recurrence step (h-part only), 2-wave k-split (r14-proven) ------------
__global__ __launch_bounds__(128) void k_step(int t, const f16* __restrict__ gx,
    const f16* __restrict__ WlinG, const float* __restrict__ bhh,
    const int* __restrict__ rtab, const int* __restrict__ ctab,
    const f16* __restrict__ hin, f16* __restrict__ hout, f16* __restrict__ hs){
  const int bid = blockIdx.x;
  const int g = bid & 7, c = bid >> 3;
  const int b0 = g * 16, j0 = c * 16;
  const int tid = threadIdx.x, w = tid >> 6, lane = tid & 63, l16 = lane & 15, lg = lane >> 4;

  __shared__ __align__(16) float part[64][13];
  __shared__ __align__(16) f16 ttile[16 * TP];

  int rt[4], ct[4];
  #pragma unroll
  for (int q = 0; q < 4; ++q){ rt[q] = rtab[lane*4+q]; ct[q] = ctab[lane*4+q]; }

  // wave 0: issue epilogue operands early (overlap with MFMA loop)
  f16x4 gR, gZ, gN;
  float hold[4], bnhv[4];
  #pragma unroll
  for (int q = 0; q < 4; ++q){ hold[q] = 0.f; bnhv[q] = 0.f; }
  if (w == 0){
    const f16* gp = gx + ((((size_t)(t & 31)) * 8 + g) * 32 + c) * 3 * 256;
    gR = *(const f16x4*)(gp + 0 * 256 + lane * 4);
    gZ = *(const f16x4*)(gp + 1 * 256 + lane * 4);
    gN = *(const f16x4*)(gp + 2 * 256 + lane * 4);
    #pragma unroll
    for (int q = 0; q < 4; ++q){
      hold[q] = (float)hin[(size_t)(b0 + rt[q]) * H_ + j0 + ct[q]];
      bnhv[q] = bhh[2 * H_ + j0 + ct[q]];
    }
  }

  const f16* wbase = WlinG + ((size_t)c * NFRAG * 64 + lane) * 8;
  const f16* hrow  = hin + (size_t)(b0 + l16) * H_ + lg * 8;

  f32x4 aR, aZ, aNh;
  #pragma unroll
  for (int q = 0; q < 4; ++q){ aR[q] = 0.f; aZ[q] = 0.f; aNh[q] = 0.f; }

  const int k0 = w * 8;
  #pragma unroll
  for (int kt = 0; kt < 8; ++kt){
    const int kk = k0 + kt;
    f16x8 a  = *(const f16x8*)(hrow + kk * 32);
    f16x8 w0 = *(const f16x8*)(wbase + (size_t)(kk*3+0) * 512);
    f16x8 w1 = *(const f16x8*)(wbase + (size_t)(kk*3+1) * 512);
    f16x8 w2 = *(const f16x8*)(wbase + (size_t)(kk*3+2) * 512);
    aR  = MFMA16(a, w0, aR);
    aZ  = MFMA16(a, w1, aZ);
    aNh = MFMA16(a, w2, aNh);
  }

  if (w == 1){
    #pragma unroll
    for (int q = 0; q < 4; ++q){
      part[lane][q]     = aR[q];
      part[lane][4 + q] = aZ[q];
      part[lane][8 + q] = aNh[q];
    }
  }
  __syncthreads();

  if (w == 0){
    #pragma unroll
    for (int q = 0; q < 4; ++q){
      float R  = aR[q]  + part[lane][q]     + (float)gR[q];
      float Z  = aZ[q]  + part[lane][4 + q] + (float)gZ[q];
      float Nh = aNh[q] + part[lane][8 + q] + bnhv[q];
      float r  = sigm(R);
      float z  = sigm(Z);
      float nn = tanh_f((float)gN[q] + r * Nh);
      float h  = (1.f - z) * nn + z * hold[q];
      ttile[rt[q] * TP + ct[q]] = (f16)h;
    }
    asm volatile("s_waitcnt lgkmcnt(0)" ::: "memory");
    const int rr = lane >> 2, c4 = (lane & 3) * 4;
    f16x4 tv = *(const f16x4*)&ttile[rr * TP + c4];
    unsigned long long pk;
    __builtin_memcpy(&pk, &tv, 8);
    *(unsigned long long*)(hout + (size_t)(b0 + rr) * H_ + j0 + c4) = pk;
    *(unsigned long long*)(hs + ((size_t)t * B_ + b0 + rr) * H_ + j0 + c4) = pk;
  }
}

// ---------------- fused attention (r13/r14-proven) ----------------
__global__ __launch_bounds__(256, 1) void k_att(const f16* __restrict__ hs,
    const f16* __restrict__ Wat2, const int* __restrict__ rtab, const int* __restrict__ ctab,
    float* __restrict__ out){
  const int b  = blockIdx.x >> 1;
  const int jh = blockIdx.x & 1;
  const int tid = threadIdx.x, wv = tid >> 6, lane = tid & 63, l16 = lane & 15, lg = lane >> 4;
  const int jb = jh * 256 + wv * 64;

  __shared__ __align__(16) float etile[4][16 * TP];

  int rt[4], ct[4];
  #pragma unroll
  for (int q = 0; q < 4; ++q){ rt[q] = rtab[lane*4+q]; ct[q] = ctab[lane*4+q]; }

  f16x8 ones;
  #pragma unroll
  for (int e = 0; e < 8; ++e) ones[e] = (f16)0.f;
  if (lg == 0) ones[0] = (f16)1.f;

  float num[4][4], den[4][4];
  #pragma unroll
  for (int nt = 0; nt < 4; ++nt)
    #pragma unroll
    for (int k = 0; k < 4; ++k){ num[nt][k] = 0.f; den[nt][k] = 0.f; }

  for (int tt = 0; tt < 32; ++tt){
    f16x8 a[16];
    const f16* ar = hs + ((size_t)(tt*16 + l16) * B_ + b) * H_ + lg * 8;
    #pragma unroll
    for (int kt = 0; kt < 16; ++kt) a[kt] = *(const f16x8*)(ar + kt * 32);

    #pragma unroll
    for (int nt = 0; nt < 4; ++nt){
      f32x4 acc;
      #pragma unroll
      for (int q = 0; q < 4; ++q) acc[q] = 0.f;
      const f16* wr = Wat2 + (size_t)(jb + nt*16 + l16) * KA2 + lg * 8;
      #pragma unroll
      for (int kt = 0; kt < 16; ++kt){
        f16x8 bf = *(const f16x8*)(wr + kt * 32);
        acc = MFMA16(a[kt], bf, acc);
      }
      { f16x8 bf = *(const f16x8*)(wr + 512); acc = MFMA16(ones, bf, acc); }

      #pragma unroll
      for (int q = 0; q < 4; ++q)
        etile[wv][rt[q] * TP + ct[q]] = fast_exp(tanh_f(acc[q]));
      asm volatile("s_waitcnt lgkmcnt(0)" ::: "memory");
      f32x4 ev = *(const f32x4*)&etile[wv][(lane>>2) * TP + (lane & 3) * 4];
      const f16* hp = hs + ((size_t)(tt*16 + (lane>>2)) * B_ + b) * H_ + jb + nt*16 + (lane&3)*4;
      f16x4 hv = *(const f16x4*)hp;
      #pragma unroll
      for (int k = 0; k < 4; ++k){
        num[nt][k] = fmaf(ev[k], (float)hv[k], num[nt][k]);
        den[nt][k] += ev[k];
      }
    }
  }

  #pragma unroll
  for (int nt = 0; nt < 4; ++nt){
    #pragma unroll
    for (int k = 0; k < 4; ++k){
      float n = num[nt][k], d = den[nt][k];
      #pragma unroll
      for (int m = 4; m <= 32; m <<= 1){ n += __shfl_xor(n, m, 64); d += __shfl_xor(d, m, 64); }
      if (lane < 4) out[(size_t)b * H_ + jb + nt*16 + lane*4 + k] = n / d;
    }
  }
}

extern "C" void kernel_launch(void* const* d_in, const int* in_sizes, int n_in,
                              void* d_out, int out_size, void* d_ws, size_t ws_size,
                              hipStream_t stream){
  (void)in_sizes; (void)n_in; (void)out_size;
  const float* x    = (const float*)d_in[0];
  const float* Wih  = (const float*)d_in[1];
  const float* Whh  = (const float*)d_in[2];
  const float* bih  = (const float*)d_in[3];
  const float* bhh  = (const float*)d_in[4];
  const float* Watt = (const float*)d_in[5];
  const float* batt = (const float*)d_in[6];

  char* ws = (char*)d_ws;
  // layout (bytes):
  //   hs   : [T][B][H] f16            @ 0            (67,108,864)
  //   x16  : [B][T][I] f16            @ 67,108,864   (33,554,432)
  //   WlinG: [32][78][64][8] f16      @ 100,663,296  (2,555,904)
  //   Wat2 : [512][544] f16           @ 103,219,200  (557,056)
  //   rtab : int[256]                 @ 103,776,256  (1,024)
  //   ctab : int[256]                 @ 103,777,280  (1,024)
  //   hA   : [128][512] f16           @ 103,778,304  (131,072)
  //   hB   : [128][512] f16           @ 103,909,376  (131,072)
  //   gx0  : [32][8][32][3][256] f16  @ 104,040,448  (12,582,912)
  //   gx1  : same                     @ 116,623,360  (12,582,912)
  const size_t OFF_HS  = 0ull;
  const size_t OFF_X16 = 67108864ull;
  const size_t OFF_WLG = 100663296ull;
  const size_t OFF_WAT = 103219200ull;
  const size_t OFF_RT  = 103776256ull;
  const size_t OFF_CT  = 103777280ull;
  const size_t OFF_HA  = 103778304ull;
  const size_t OFF_HB  = 103909376ull;
  const size_t OFF_GX0 = 104040448ull;
  const size_t OFF_GX1 = 116623360ull;
  const size_t NEED    = 129206272ull;   // <= 137,332,736 proven available
  if (ws_size < NEED) return;

  f16* hs    = (f16*)(ws + OFF_HS);
  f16* x16   = (f16*)(ws + OFF_X16);
  f16* WlinG = (f16*)(ws + OFF_WLG);
  f16* Wat2  = (f16*)(ws + OFF_WAT);
  int* rtab  = (int*)(ws + OFF_RT);
  int* ctab  = (int*)(ws + OFF_CT);
  f16* hA    = (f16*)(ws + OFF_HA);
  f16* hB    = (f16*)(ws + OFF_HB);
  f16* gxb[2] = { (f16*)(ws + OFF_GX0), (f16*)(ws + OFF_GX1) };

  // h(-1) = 0 every launch
  hipMemsetAsync(ws + OFF_HA, 0, 131072, stream);

  k_prep <<<2048, 256, 0, stream>>>(x, Wih, Whh, bih, bhh, Watt, batt, WlinG, Wat2, x16);
  k_probe<<<1,    64,  0, stream>>>(rtab, ctab);
  k_xg   <<<256,  256, 0, stream>>>(0, x16, WlinG, gxb[0]);

  for (int t = 0; t < T_; ++t){
    const f16* hin  = (t & 1) ? hB : hA;
    f16*       hout = (t & 1) ? hA : hB;
    k_step<<<256, 128, 0, stream>>>(t, gxb[(t >> 5) & 1], WlinG, bhh, rtab, ctab, hin, hout, hs);
    if ((t & 31) == 0 && t + 32 < T_)
      k_xg<<<256, 256, 0, stream>>>(t + 32, x16, WlinG, gxb[((t >> 5) + 1) & 1]);
  }

  k_att<<<256, 256, 0, stream>>>(hs, Wat2, rtab, ctab, (float*)d_out);
}